// Round 12
// baseline (219.884 us; speedup 1.0000x reference)
//
#include <hip/hip_runtime.h>
#include <hip/hip_bf16.h>
#include <math.h>

#define BB 4
#define VV 1024
#define HH 128
#define H2 64
#define EE 523776               // V*(V-1)/2
#define BE (BB * EE)            // 2095104
#define TPB64 (EE / 64)         // 8184 64-edge tiles per batch (exact)
#define NT64 (BE / 64)          // 32736
#define NTHR 256
#define NBLK 1024
#define NWAVE (NBLK * 4)        // 4096

typedef __attribute__((ext_vector_type(8))) short bf16x8;
typedef __attribute__((ext_vector_type(4))) float f32x4;
typedef __attribute__((ext_vector_type(4))) unsigned u32x4;

__device__ __forceinline__ short f2bf(float f) {
    __hip_bfloat16 h = __float2bfloat16(f);
    return *reinterpret_cast<short*>(&h);
}

// ONE v_perm_b32: pack two f32 into bf16x2 by truncation (lo -> low half).
__device__ __forceinline__ unsigned pkbf(float lo, float hi) {
    return __builtin_amdgcn_perm(__float_as_uint(hi), __float_as_uint(lo),
                                 0x07060302u);
}

__device__ __forceinline__ bf16x8 relu_pack(f32x4 a, f32x4 b) {
    u32x4 r;
    r[0] = pkbf(fmaxf(a[0], 0.f), fmaxf(a[1], 0.f));
    r[1] = pkbf(fmaxf(a[2], 0.f), fmaxf(a[3], 0.f));
    r[2] = pkbf(fmaxf(b[0], 0.f), fmaxf(b[1], 0.f));
    r[3] = pkbf(fmaxf(b[2], 0.f), fmaxf(b[3], 0.f));
    return __builtin_bit_cast(bf16x8, r);
}

// ---------------------------------------------------------------------------
// Round 12: zero persistent weight registers (R3-R11 were occupancy-capped at
// 2 waves/SIMD by ~64-128 AGPR-resident weights; VGPR_Count hides AGPRs).
// ALL weights live in per-lane LDS frag tables (16B/lane ds_read_b128,
// conflict-free); only the d2 accumulators occupy AGPRs (their natural home).
// 64-edge tiles: 4 sub-tiles share every weight-frag read (LDS traffic /2)
// and give 4 independent MFMA chains of in-wave ILP. Fragment layouts
// identical to R11 (L1 row-perm -> L2 B-frag; A2 row-perm -> L3 B-frag;
// b1 folded in feature k=6; b2 as C-init; b3 as L3 C-init).
// ---------------------------------------------------------------------------
__global__ __launch_bounds__(NTHR, 3) void edge_mlp_v12(
    const float* __restrict__ vertices,  // [4,1024,3]
    const float* __restrict__ W1,        // [6,128]
    const float* __restrict__ b1,        // [128]
    const float* __restrict__ W2,        // [128,64]
    const float* __restrict__ b2,        // [64]
    const float* __restrict__ W3,        // [64]
    const float* __restrict__ b3,        // [1]
    float* __restrict__ out)             // [BE probs][2*EE indices-as-float]
{
    // frag ids: 0..7 = A1[p][q1] (id=2p+q1), 8..23 = A2[mt][p] (id=8+4mt+p),
    //           24..25 = A3[t]
    __shared__ __align__(16) bf16x8 wA[26 * 64];     // 26 KB
    __shared__ __align__(16) f32x4  wC[4 * 64];      // 4 KB  b2 C-init

    const int lane = threadIdx.x & 63;
    const int col  = lane & 15;          // edge slot within a 16-edge subtile
    const int u    = lane >> 4;
    const int wid  = threadIdx.x >> 6;

    const f32x4 zero4 = {0.f, 0.f, 0.f, 0.f};

    // ---- stage all 30 frag tables (over 4 waves) ----
    for (int f = wid; f < 30; f += 4) {
        if (f < 8) {
            // A1: row m -> h = 32p + 8*(m>>2) + 4q1 + (m&3); elem r -> k=8u+r
            const int p = f >> 1, q1 = f & 1;
            const int h = 32 * p + 8 * (col >> 2) + 4 * q1 + (col & 3);
            bf16x8 a;
#pragma unroll
            for (int r = 0; r < 8; ++r) {
                const int k = 8 * u + r;
                float w = 0.0f;
                if (k < 6)       w = W1[k * HH + h];
                else if (k == 6) w = b1[h];
                a[r] = f2bf(w);
            }
            wA[f * 64 + lane] = a;
        } else if (f < 24) {
            // A2: row m -> n2 = 32*(mt>>1) + 8*(m>>2) + 4*(mt&1) + (m&3);
            //     elem r -> k = h = 32p + 8u + r   (D-layout == L3 B-frag)
            const int mt = (f - 8) >> 2, p = (f - 8) & 3;
            const int n2 = 32 * (mt >> 1) + 8 * (col >> 2) + 4 * (mt & 1) + (col & 3);
            bf16x8 a;
#pragma unroll
            for (int r = 0; r < 8; ++r)
                a[r] = f2bf(W2[(32 * p + 8 * u + r) * H2 + n2]);
            wA[f * 64 + lane] = a;
        } else if (f < 26) {
            // A3[t]: all rows identical; elem r = W3[32t + 8u + r]
            const int t = f - 24;
            bf16x8 a;
#pragma unroll
            for (int r = 0; r < 8; ++r) a[r] = f2bf(W3[32 * t + 8 * u + r]);
            wA[f * 64 + lane] = a;
        } else {
            // cinit[mt]: q-component = b2[n2(mt, row=4u+q)]
            const int mt = f - 26;
            f32x4 c;
#pragma unroll
            for (int q = 0; q < 4; ++q)
                c[q] = b2[32 * (mt >> 1) + 8 * u + 4 * (mt & 1) + q];
            wC[mt * 64 + lane] = c;
        }
    }
    const float b3v = b3[0];
    __syncthreads();

    const int gw = blockIdx.x * 4 + wid;

    for (int tt = gw; tt < NT64; tt += NWAVE) {
        const int b  = tt / TPB64;
        const int e0 = (tt - b * TPB64) * 64;

        // ---- decode + feature frags for 4 subtiles ----
        bf16x8 bfv[4];
        int iv[4], jv[4];
#pragma unroll
        for (int s = 0; s < 4; ++s) {
            const int e  = e0 + s * 16 + col;
            const int rr = EE - 1 - e;
            const float sq = sqrtf((float)(8 * rr + 1));   // exact: < 2^23
            int m = (int)(0.5f * (sq - 1.0f));
            if ((m + 1) * (m + 2) / 2 <= rr) ++m;
            if (m * (m + 1) / 2 > rr) --m;
            const int pp = rr - m * (m + 1) / 2;
            iv[s] = VV - 2 - m;
            jv[s] = VV - 1 - pp;
            const float* pvi = vertices + (b * VV + iv[s]) * 3;
            const float* pvj = vertices + (b * VV + jv[s]) * 3;
            u32x4 fb;
            fb[0] = pkbf(pvi[0], pvi[1]);
            fb[1] = pkbf(pvi[2], pvj[0]);
            fb[2] = pkbf(pvj[1], pvj[2]);
            fb[3] = 0x00003F80u;              // bf16(1.0) in k=6 carries b1
            bfv[s] = __builtin_bit_cast(bf16x8, fb);
            // (u != 0 lanes hold copies that only hit zero A1 rows: no mask)
        }

        // ---- d2 accumulators (AGPR-resident), init = b2 ----
        f32x4 d2[4][4];
#pragma unroll
        for (int mt = 0; mt < 4; ++mt) {
            const f32x4 c = wC[mt * 64 + lane];
#pragma unroll
            for (int s = 0; s < 4; ++s) d2[s][mt] = c;
        }

        // ---- fused L1 -> relu/pack -> L2; weights read ONCE per p ----
#pragma unroll
        for (int p = 0; p < 4; ++p) {
            const bf16x8 a1a = wA[(2 * p + 0) * 64 + lane];
            const bf16x8 a1b = wA[(2 * p + 1) * 64 + lane];
            const bf16x8 w20 = wA[(8 + 0 * 4 + p) * 64 + lane];
            const bf16x8 w21 = wA[(8 + 1 * 4 + p) * 64 + lane];
            const bf16x8 w22 = wA[(8 + 2 * 4 + p) * 64 + lane];
            const bf16x8 w23 = wA[(8 + 3 * 4 + p) * 64 + lane];
#pragma unroll
            for (int s = 0; s < 4; ++s) {
                const f32x4 dA = __builtin_amdgcn_mfma_f32_16x16x32_bf16(a1a, bfv[s], zero4, 0, 0, 0);
                const f32x4 dB = __builtin_amdgcn_mfma_f32_16x16x32_bf16(a1b, bfv[s], zero4, 0, 0, 0);
                const bf16x8 Bh = relu_pack(dA, dB);
                d2[s][0] = __builtin_amdgcn_mfma_f32_16x16x32_bf16(w20, Bh, d2[s][0], 0, 0, 0);
                d2[s][1] = __builtin_amdgcn_mfma_f32_16x16x32_bf16(w21, Bh, d2[s][1], 0, 0, 0);
                d2[s][2] = __builtin_amdgcn_mfma_f32_16x16x32_bf16(w22, Bh, d2[s][2], 0, 0, 0);
                d2[s][3] = __builtin_amdgcn_mfma_f32_16x16x32_bf16(w23, Bh, d2[s][3], 0, 0, 0);
            }
        }

        // ---- L3 as MFMA (D-layout of L2 IS the L3 B-frag) + store ----
        const bf16x8 a30 = wA[24 * 64 + lane];
        const bf16x8 a31 = wA[25 * 64 + lane];
#pragma unroll
        for (int s = 0; s < 4; ++s) {
            const bf16x8 Bh3_0 = relu_pack(d2[s][0], d2[s][1]);
            const bf16x8 Bh3_1 = relu_pack(d2[s][2], d2[s][3]);
            f32x4 d3 = {b3v, b3v, b3v, b3v};
            d3 = __builtin_amdgcn_mfma_f32_16x16x32_bf16(a30, Bh3_0, d3, 0, 0, 0);
            d3 = __builtin_amdgcn_mfma_f32_16x16x32_bf16(a31, Bh3_1, d3, 0, 0, 0);

            if (u == 0) {
                const float prob = __builtin_amdgcn_rcpf(1.0f + __expf(-d3[0]));
                out[tt * 64 + s * 16 + col] = prob;     // == b*EE + e0 + s*16+col
                if (b == 0) {
                    const int e = e0 + s * 16 + col;
                    *(float2*)(&out[BE + 2 * e]) =
                        make_float2((float)iv[s], (float)jv[s]);
                }
            }
        }
    }
}

extern "C" void kernel_launch(void* const* d_in, const int* in_sizes, int n_in,
                              void* d_out, int out_size, void* d_ws, size_t ws_size,
                              hipStream_t stream) {
    const float* vertices = (const float*)d_in[0];
    const float* W1 = (const float*)d_in[1];
    const float* b1 = (const float*)d_in[2];
    const float* W2 = (const float*)d_in[3];
    const float* b2 = (const float*)d_in[4];
    const float* W3 = (const float*)d_in[5];
    const float* b3 = (const float*)d_in[6];
    float* out = (float*)d_out;

    edge_mlp_v12<<<NBLK, NTHR, 0, stream>>>(vertices, W1, b1, W2, b2, W3, b3, out);
}